// Round 4
// baseline (417.381 us; speedup 1.0000x reference)
//
#include <hip/hip_runtime.h>
#include <hip/hip_bf16.h>

// Problem constants
#define IN_F   2048
#define N_CON  64
#define EMB    128
#define BATCH  8192

// Output layout (f32 elements): c_emb | c_pred | c_int | emb
#define CEMB_OFF  0
#define CPRED_OFF 67108864   // 8192*64*128
#define CINT_OFF  67633152   // + 8192*64
#define EMB_OFF   68157440   // + 8192*64

typedef __attribute__((ext_vector_type(4))) float f32x4;
typedef __attribute__((ext_vector_type(8))) short short8;
typedef __attribute__((ext_vector_type(4))) short short4v;

#define MFMA16(A,B,C) __builtin_amdgcn_mfma_f32_16x16x32_bf16((A),(B),(C),0,0,0)

__device__ __forceinline__ short f2bf(float f) {
  unsigned u = __float_as_uint(f);
  u += 0x7FFFu + ((u >> 16) & 1u);   // round-to-nearest-even
  return (short)(u >> 16);
}

__device__ __forceinline__ void gload_lds16(const void* g, void* l) {
  __builtin_amdgcn_global_load_lds(
      (const __attribute__((address_space(1))) unsigned*)g,
      (__attribute__((address_space(3))) unsigned*)l, 16, 0, 0);
}

// ---------------- kernel 0: f32 -> bf16 convert (We + Wc merged) ----------------
__global__ void conv2_kernel(const float* __restrict__ a, short* __restrict__ da, int n4a,
                             const float* __restrict__ b, short* __restrict__ db, int n4b) {
  int i = blockIdx.x * blockDim.x + threadIdx.x;
  const float* s; short* d; int j;
  if (i < n4a)            { s = a; d = da; j = i; }
  else if (i < n4a + n4b) { s = b; d = db; j = i - n4a; }
  else return;
  f32x4 v = *(const f32x4*)(s + (size_t)j * 4);
  short4v o;
  o.x = f2bf(v.x); o.y = f2bf(v.y); o.z = f2bf(v.z); o.w = f2bf(v.w);
  *(short4v*)(d + (size_t)j * 4) = o;
}

// ---------------- kernel 1: emb = leaky(x @ We^T + be) ----------------
// BM=16, grid 512, 256 threads (4 waves), LDS 36 KB -> 4 blocks/CU.
__global__ __launch_bounds__(256, 4)
void gemm1_kernel(const float* __restrict__ x,
                  const short* __restrict__ we_bf,   // [128][2048] bf16
                  const float* __restrict__ be,
                  float* __restrict__ out_emb,       // [8192][128] f32
                  short* __restrict__ emb_bf) {      // [8192][128] bf16
  __shared__ short As[16 * 128];    // 4 KB, XOR-swizzled
  __shared__ short Bs[128 * 128];   // 32 KB, XOR-swizzled

  const int t = threadIdx.x;
  const int w = t >> 6, l = t & 63;
  const int row0 = blockIdx.x * 16;

  f32x4 acc[2];
  acc[0] = (f32x4){0.f, 0.f, 0.f, 0.f};
  acc[1] = (f32x4){0.f, 0.f, 0.f, 0.f};

  const int ar = t >> 4;
  const int aseg = t & 15;
  const float* xrow = x + (size_t)(row0 + ar) * IN_F + aseg * 8;
  short* adst = &As[ar * 128 + ((aseg * 8) ^ ((ar & 7) << 3))];

  const int brl = t >> 4;
  const int bseg = l & 15;

  for (int kt = 0; kt < 16; ++kt) {
    const int k0 = kt * 128;
    {
      f32x4 v0 = *(const f32x4*)(xrow + k0);
      f32x4 v1 = *(const f32x4*)(xrow + k0 + 4);
      short8 o;
      o[0] = f2bf(v0.x); o[1] = f2bf(v0.y); o[2] = f2bf(v0.z); o[3] = f2bf(v0.w);
      o[4] = f2bf(v1.x); o[5] = f2bf(v1.y); o[6] = f2bf(v1.z); o[7] = f2bf(v1.w);
      *(short8*)adst = o;
    }
#pragma unroll
    for (int i = 0; i < 8; ++i) {
      int n = i * 16 + brl;
      gload_lds16(we_bf + (size_t)n * IN_F + k0 + ((bseg ^ (n & 7)) * 8),
                  &Bs[i * 2048 + w * 512]);
    }
    __syncthreads();
#pragma unroll
    for (int ks = 0; ks < 4; ++ks) {
      int kcol = ks * 32 + ((l >> 4) << 3);
      int r0 = l & 15;
      short8 a = *(const short8*)&As[r0 * 128 + (kcol ^ ((r0 & 7) << 3))];
      int n0 = w * 32 + (l & 15), n1 = n0 + 16;
      short8 b0 = *(const short8*)&Bs[n0 * 128 + (kcol ^ ((n0 & 7) << 3))];
      short8 b1 = *(const short8*)&Bs[n1 * 128 + (kcol ^ ((n1 & 7) << 3))];
      acc[0] = MFMA16(a, b0, acc[0]);
      acc[1] = MFMA16(a, b1, acc[1]);
    }
    __syncthreads();
  }

#pragma unroll
  for (int nf = 0; nf < 2; ++nf) {
    int e = w * 32 + nf * 16 + (l & 15);
    float bev = be[e];
#pragma unroll
    for (int r = 0; r < 4; ++r) {
      int b = row0 + ((l >> 4) << 2) + r;
      float v = acc[nf][r] + bev;
      v = v >= 0.f ? v : 0.01f * v;
      out_emb[(size_t)b * EMB + e] = v;
      emb_bf[(size_t)b * EMB + e] = f2bf(v);
    }
  }
}

// ---------------- kernel 2: fused context/gate/c_emb (v3) ----------------
// Grid 1024 = 16 m-chunks x 64 concepts. Block = 256 thr (4 waves).
// B (Wc[kc], 64 KB) staged ONCE into LDS; ONE barrier; then a barrier-free
// m-loop: 4 iters x (4 waves x 32 rows). A-frags read directly from global
// (emb_bf is L2-resident, 16 rows x 64 B contiguous segments per load).
// acc[2][16] (~128 VGPR) halves B LDS re-reads vs 16-row waves.
// Bias folded into MFMA C-init; leaky = max(v, 0.01v).
__global__ __launch_bounds__(256, 2)
void gemm2_kernel(const short* __restrict__ emb_bf,  // [8192][128] bf16
                  const short* __restrict__ wc_bf,   // [64][256][128] bf16
                  const float* __restrict__ bc,      // [64][256]
                  const float* __restrict__ wp,      // [256]
                  const float* __restrict__ bp,      // [1]
                  float* __restrict__ ws_pred,       // [64][8192]
                  float* __restrict__ out) {
  __shared__ short Bs[256 * 128];   // 64 KB -> 2 blocks/CU

  const int t = threadIdx.x;
  const int w = t >> 6, l = t & 63;
  const int kc = blockIdx.x & 63;
  const int mch = (blockIdx.x >> 6) * 512;

  // stage B once: 16 issues x 4 KB (pre-swizzled source, linear LDS dest)
  const int rl = t >> 4;
  const int seg = l & 15;
#pragma unroll
  for (int i = 0; i < 16; ++i) {
    int rB = i * 16 + rl;
    gload_lds16(wc_bf + (size_t)kc * 32768 + (size_t)rB * 128 + ((seg ^ (rB & 7)) * 8),
                &Bs[i * 2048 + w * 512]);
  }

  float wph[16], bcv[16];
#pragma unroll
  for (int nf = 0; nf < 16; ++nf) {
    wph[nf] = wp[nf * 16 + (l & 15)];
    bcv[nf] = bc[kc * 256 + nf * 16 + (l & 15)];
  }
  const float bp0 = bp[0];

  __syncthreads();   // drains vmcnt -> B ready; no barriers after this

  const int lq = (l >> 4) << 3;   // k sub-offset per lane group

  for (int it = 0; it < 4; ++it) {
    const int rbase = mch + it * 128 + w * 32 + (l & 15);

    // A-frags direct from global (L2): 2 m-frags x 4 k-slices
    short8 a[2][4];
#pragma unroll
    for (int mf = 0; mf < 2; ++mf)
#pragma unroll
      for (int ks = 0; ks < 4; ++ks)
        a[mf][ks] = *(const short8*)&emb_bf[(size_t)(rbase + mf * 16) * 128 + ks * 32 + lq];

    f32x4 acc[2][16];
#pragma unroll
    for (int mf = 0; mf < 2; ++mf)
#pragma unroll
      for (int nf = 0; nf < 16; ++nf)
        acc[mf][nf] = (f32x4){bcv[nf], bcv[nf], bcv[nf], bcv[nf]};

#pragma unroll
    for (int ks = 0; ks < 4; ++ks) {
      int kcol = ks * 32 + lq;
#pragma unroll
      for (int nf = 0; nf < 16; ++nf) {
        int n = nf * 16 + (l & 15);
        short8 b = *(const short8*)&Bs[n * 128 + (kcol ^ ((n & 7) << 3))];
        acc[0][nf] = MFMA16(a[0][ks], b, acc[0][nf]);
        acc[1][nf] = MFMA16(a[1][ks], b, acc[1][nf]);
      }
    }

    // epilogue: leaky, wp-dot (shfl over 16 lanes), sigmoid, gate, store
#pragma unroll
    for (int mf = 0; mf < 2; ++mf) {
      f32x4 p = (f32x4){0.f, 0.f, 0.f, 0.f};
#pragma unroll
      for (int nf = 0; nf < 16; ++nf) {
#pragma unroll
        for (int r = 0; r < 4; ++r) {
          float v = acc[mf][nf][r];
          v = fmaxf(v, 0.01f * v);      // leaky_relu
          acc[mf][nf][r] = v;
          p[r] += v * wph[nf];
        }
      }
      float g[4];
#pragma unroll
      for (int r = 0; r < 4; ++r) {
        float s = p[r];
        s += __shfl_xor(s, 1);
        s += __shfl_xor(s, 2);
        s += __shfl_xor(s, 4);
        s += __shfl_xor(s, 8);
        g[r] = 1.f / (1.f + __expf(-(s + bp0)));
      }

      const int rowb = mch + it * 128 + w * 32 + mf * 16 + ((l >> 4) << 2);
      if ((l & 15) == 0) {
        f32x4 gv; gv.x = g[0]; gv.y = g[1]; gv.z = g[2]; gv.w = g[3];
        *(f32x4*)&ws_pred[(size_t)kc * 8192 + rowb] = gv;
      }
#pragma unroll
      for (int r = 0; r < 4; ++r) {
        int brow = rowb + r;
        float gg = g[r];
#pragma unroll
        for (int nf = 0; nf < 8; ++nf) {
          float pos = acc[mf][nf][r], neg = acc[mf][nf + 8][r];
          out[(size_t)brow * 8192 + kc * 128 + nf * 16 + (l & 15)] = neg + (pos - neg) * gg;
        }
      }
    }
  }
}

// ---------------- kernel 3: transpose ws_pred -> c_pred, c_int ----------------
__global__ __launch_bounds__(256)
void pred_tr_kernel(const float* __restrict__ ws_pred, float* __restrict__ out) {
  __shared__ float T[64][65];
  const int t = threadIdx.x;
  const int b0 = blockIdx.x * 64;

  {
    int kc = t >> 2;
    int j0 = (t & 3) * 16;
    const float* src = ws_pred + (size_t)kc * 8192 + b0 + j0;
#pragma unroll
    for (int i = 0; i < 4; ++i) {
      f32x4 v = *(const f32x4*)(src + i * 4);
      T[kc][j0 + i * 4 + 0] = v.x;
      T[kc][j0 + i * 4 + 1] = v.y;
      T[kc][j0 + i * 4 + 2] = v.z;
      T[kc][j0 + i * 4 + 3] = v.w;
    }
  }
  __syncthreads();
  {
    int bl = t & 63;
    int kq = (t >> 6) * 16;
#pragma unroll
    for (int i = 0; i < 4; ++i) {
      f32x4 v;
      v.x = T[kq + i * 4 + 0][bl];
      v.y = T[kq + i * 4 + 1][bl];
      v.z = T[kq + i * 4 + 2][bl];
      v.w = T[kq + i * 4 + 3][bl];
      *(f32x4*)&out[CPRED_OFF + (size_t)(b0 + bl) * 64 + kq + i * 4] = v;
      *(f32x4*)&out[CINT_OFF + (size_t)(b0 + bl) * 64 + kq + i * 4] = v;
    }
  }
}

extern "C" void kernel_launch(void* const* d_in, const int* in_sizes, int n_in,
                              void* d_out, int out_size, void* d_ws, size_t ws_size,
                              hipStream_t stream) {
  (void)in_sizes; (void)n_in; (void)out_size; (void)ws_size;
  const float* x  = (const float*)d_in[0];
  const float* We = (const float*)d_in[1];
  const float* be = (const float*)d_in[2];
  const float* Wc = (const float*)d_in[3];
  const float* bc = (const float*)d_in[4];
  const float* wp = (const float*)d_in[5];
  const float* bp = (const float*)d_in[6];
  float* out = (float*)d_out;

  // ws layout: We_bf16 (512KB) | Wc_bf16 (4MB) | emb_bf16 (2MB) | ws_pred (2MB f32)
  short* we_bf  = (short*)d_ws;
  short* wc_bf  = we_bf + 262144;
  short* emb_bf = wc_bf + 2097152;
  float* ws_pred = (float*)(emb_bf + 1048576);

  conv2_kernel<<<2304, 256, 0, stream>>>(We, we_bf, 65536, Wc, wc_bf, 524288);
  gemm1_kernel<<<512, 256, 0, stream>>>(x, we_bf, be, out + EMB_OFF, emb_bf);
  gemm2_kernel<<<1024, 256, 0, stream>>>(emb_bf, wc_bf, bc, wp, bp, ws_pred, out);
  pred_tr_kernel<<<128, 256, 0, stream>>>(ws_pred, out);
}

// Round 5
// 129.211 us; speedup vs baseline: 3.2302x; 3.2302x over previous
//
#include <hip/hip_runtime.h>
#include <hip/hip_bf16.h>

// Problem constants
#define IN_F   2048
#define N_CON  64
#define EMB    128
#define BATCH  8192

// Output layout (f32 elements): c_emb | c_pred | c_int | emb
#define CEMB_OFF  0
#define CPRED_OFF 67108864   // 8192*64*128
#define CINT_OFF  67633152   // + 8192*64
#define EMB_OFF   68157440   // + 8192*64

typedef __attribute__((ext_vector_type(4))) float f32x4;
typedef __attribute__((ext_vector_type(8))) short short8;
typedef __attribute__((ext_vector_type(4))) short short4v;

#define MFMA16(A,B,C) __builtin_amdgcn_mfma_f32_16x16x32_bf16((A),(B),(C),0,0,0)

__device__ __forceinline__ short f2bf(float f) {
  unsigned u = __float_as_uint(f);
  u += 0x7FFFu + ((u >> 16) & 1u);   // round-to-nearest-even
  return (short)(u >> 16);
}

__device__ __forceinline__ void gload_lds16(const void* g, void* l) {
  __builtin_amdgcn_global_load_lds(
      (const __attribute__((address_space(1))) unsigned*)g,
      (__attribute__((address_space(3))) unsigned*)l, 16, 0, 0);
}

// ---------------- kernel 0: f32 -> bf16 convert (We + Wc merged) ----------------
__global__ void conv2_kernel(const float* __restrict__ a, short* __restrict__ da, int n4a,
                             const float* __restrict__ b, short* __restrict__ db, int n4b) {
  int i = blockIdx.x * blockDim.x + threadIdx.x;
  const float* s; short* d; int j;
  if (i < n4a)            { s = a; d = da; j = i; }
  else if (i < n4a + n4b) { s = b; d = db; j = i - n4a; }
  else return;
  f32x4 v = *(const f32x4*)(s + (size_t)j * 4);
  short4v o;
  o.x = f2bf(v.x); o.y = f2bf(v.y); o.z = f2bf(v.z); o.w = f2bf(v.w);
  *(short4v*)(d + (size_t)j * 4) = o;
}

// ---------------- kernel 1: emb = leaky(x @ We^T + be) ----------------
// BM=16, grid 512, 256 threads (4 waves), LDS 36 KB -> 4 blocks/CU.
__global__ __launch_bounds__(256, 4)
void gemm1_kernel(const float* __restrict__ x,
                  const short* __restrict__ we_bf,   // [128][2048] bf16
                  const float* __restrict__ be,
                  float* __restrict__ out_emb,       // [8192][128] f32
                  short* __restrict__ emb_bf) {      // [8192][128] bf16
  __shared__ short As[16 * 128];    // 4 KB, XOR-swizzled
  __shared__ short Bs[128 * 128];   // 32 KB, XOR-swizzled

  const int t = threadIdx.x;
  const int w = t >> 6, l = t & 63;
  const int row0 = blockIdx.x * 16;

  f32x4 acc[2];
  acc[0] = (f32x4){0.f, 0.f, 0.f, 0.f};
  acc[1] = (f32x4){0.f, 0.f, 0.f, 0.f};

  const int ar = t >> 4;
  const int aseg = t & 15;
  const float* xrow = x + (size_t)(row0 + ar) * IN_F + aseg * 8;
  short* adst = &As[ar * 128 + ((aseg * 8) ^ ((ar & 7) << 3))];

  const int brl = t >> 4;
  const int bseg = l & 15;

  for (int kt = 0; kt < 16; ++kt) {
    const int k0 = kt * 128;
    {
      f32x4 v0 = *(const f32x4*)(xrow + k0);
      f32x4 v1 = *(const f32x4*)(xrow + k0 + 4);
      short8 o;
      o[0] = f2bf(v0.x); o[1] = f2bf(v0.y); o[2] = f2bf(v0.z); o[3] = f2bf(v0.w);
      o[4] = f2bf(v1.x); o[5] = f2bf(v1.y); o[6] = f2bf(v1.z); o[7] = f2bf(v1.w);
      *(short8*)adst = o;
    }
#pragma unroll
    for (int i = 0; i < 8; ++i) {
      int n = i * 16 + brl;
      gload_lds16(we_bf + (size_t)n * IN_F + k0 + ((bseg ^ (n & 7)) * 8),
                  &Bs[i * 2048 + w * 512]);
    }
    __syncthreads();
#pragma unroll
    for (int ks = 0; ks < 4; ++ks) {
      int kcol = ks * 32 + ((l >> 4) << 3);
      int r0 = l & 15;
      short8 a = *(const short8*)&As[r0 * 128 + (kcol ^ ((r0 & 7) << 3))];
      int n0 = w * 32 + (l & 15), n1 = n0 + 16;
      short8 b0 = *(const short8*)&Bs[n0 * 128 + (kcol ^ ((n0 & 7) << 3))];
      short8 b1 = *(const short8*)&Bs[n1 * 128 + (kcol ^ ((n1 & 7) << 3))];
      acc[0] = MFMA16(a, b0, acc[0]);
      acc[1] = MFMA16(a, b1, acc[1]);
    }
    __syncthreads();
  }

#pragma unroll
  for (int nf = 0; nf < 2; ++nf) {
    int e = w * 32 + nf * 16 + (l & 15);
    float bev = be[e];
#pragma unroll
    for (int r = 0; r < 4; ++r) {
      int b = row0 + ((l >> 4) << 2) + r;
      float v = acc[nf][r] + bev;
      v = v >= 0.f ? v : 0.01f * v;
      out_emb[(size_t)b * EMB + e] = v;
      emb_bf[(size_t)b * EMB + e] = f2bf(v);
    }
  }
}

// ---------------- kernel 2: fused context/gate/c_emb (v5) ----------------
// Grid 1024 = 16 m-chunks(512 rows) x 64 concepts. Block = 512 thr (8 waves).
// Waves pair up: pair p = waves (2p, 2p+1); half h = w&1.
//   half 0 owns col-groups {0..3, 8..11} (cols 0-63, 128-191)
//   half 1 owns col-groups {4..7, 12..15} (cols 64-127, 192-255)
// so pos (e) / neg (e+128) gating is IN-LANE. B (Wc[kc]) lives in REGISTERS
// (128 VGPR/wave), loaded once via LDS; LDS is then recycled as per-wave
// double-buffered A staging (4 KB x 2 per wave) filled by global_load_lds.
// Sync discipline: stores are NEVER drained. Per iter:
//   - per-wave counted s_waitcnt vmcnt(17) retires own A-prefetch
//     (4 loads older than exactly 17 stores: 16 c_emb dword + 1 gv dwordx4)
//   - one lgkmcnt(0)+s_barrier for the wp-dot partial exchange (parity-dbuf)
__global__ __launch_bounds__(512, 2)
void gemm2_kernel(const short* __restrict__ emb_bf,  // [8192][128] bf16
                  const short* __restrict__ wc_bf,   // [64][256][128] bf16
                  const float* __restrict__ bc,      // [64][256]
                  const float* __restrict__ wp,      // [256]
                  const float* __restrict__ bp,      // [1]
                  float* __restrict__ ws_pred,       // [64][8192]
                  float* __restrict__ out) {
  __shared__ short smem[32768];     // 64 KB: Bs (prologue) -> A buffers (loop)
  __shared__ float pairbuf[256];    // dot-partial exchange, parity-dbuf

  const int t = threadIdx.x;
  const int w = t >> 6, l = t & 63;
  const int h = w & 1;              // half within pair
  const int p = w >> 1;             // pair 0..3
  const int q = l >> 4;             // lane quarter
  const int li = l & 15;
  const int lq = q << 3;
  const int kc = blockIdx.x & 63;
  const int mch = (blockIdx.x >> 6) * 512;

  // ---- prologue: stage B (64 KB) coalesced, then read into registers ----
  {
    const int rl = t >> 4;          // 0..31
#pragma unroll
    for (int i = 0; i < 8; ++i) {
      int rB = i * 32 + rl;
      gload_lds16(wc_bf + (size_t)kc * 32768 + (size_t)rB * 128 + ((li ^ (rB & 7)) * 8),
                  smem + i * 4096 + w * 512);
    }
  }
  float wph[8], bcv[8];
#pragma unroll
  for (int i = 0; i < 8; ++i) {
    int gg = (i & 3) + h * 4 + (i >> 2) * 8;
    wph[i] = wp[gg * 16 + li];
    bcv[i] = bc[kc * 256 + gg * 16 + li];
  }
  const float bp0 = bp[0];
  __syncthreads();                  // B in LDS

  short8 b[8][4];
#pragma unroll
  for (int i = 0; i < 8; ++i) {
    int gg = (i & 3) + h * 4 + (i >> 2) * 8;
    int n = gg * 16 + li;
#pragma unroll
    for (int ks = 0; ks < 4; ++ks)
      b[i][ks] = *(const short8*)&smem[n * 128 + ((ks * 32 + lq) ^ ((n & 7) << 3))];
  }
  __syncthreads();                  // all waves done reading B; recycle smem

  // per-wave A double-buffer: 4096 shorts (8 KB) at smem + w*4096
  short* bufA = smem + w * 4096;
  const int R0 = mch + p * 16;

  // stage A(0) into buf half 0 (own wave only)
#pragma unroll
  for (int j = 0; j < 4; ++j) {
    int r = j * 4 + q;
    gload_lds16(emb_bf + (size_t)(R0 + r) * 128 + ((li ^ (r & 7)) * 8),
                bufA + j * 512);
  }
  asm volatile("s_waitcnt vmcnt(0)" ::: "memory");   // no stores yet: cheap

  int cur = 0;
  for (int it = 0; it < 8; ++it) {
    // A fragments from own buffer
    short8 a[4];
#pragma unroll
    for (int ks = 0; ks < 4; ++ks)
      a[ks] = *(const short8*)&bufA[cur * 2048 + li * 128 + ((ks * 32 + lq) ^ ((li & 7) << 3))];

    // prefetch A(it+1) into other half (counts 4 in vmcnt, older than stores)
    if (it < 7) {
#pragma unroll
      for (int j = 0; j < 4; ++j) {
        int r = j * 4 + q;
        gload_lds16(emb_bf + (size_t)(R0 + (it + 1) * 64 + r) * 128 + ((li ^ (r & 7)) * 8),
                    bufA + (cur ^ 1) * 2048 + j * 512);
      }
    }

    // MFMA: 8 col-groups x 4 k-slices, C-init = bc
    f32x4 acc[8];
#pragma unroll
    for (int i = 0; i < 8; ++i)
      acc[i] = (f32x4){bcv[i], bcv[i], bcv[i], bcv[i]};
#pragma unroll
    for (int ks = 0; ks < 4; ++ks)
#pragma unroll
      for (int i = 0; i < 8; ++i)
        acc[i] = MFMA16(a[ks], b[i][ks], acc[i]);

    // leaky + own-half wp-dot
    f32x4 ps = (f32x4){0.f, 0.f, 0.f, 0.f};
#pragma unroll
    for (int i = 0; i < 8; ++i)
#pragma unroll
      for (int r = 0; r < 4; ++r) {
        float v = acc[i][r];
        v = fmaxf(v, 0.01f * v);
        acc[i][r] = v;
        ps[r] += v * wph[i];
      }
#pragma unroll
    for (int r = 0; r < 4; ++r) {
      float s = ps[r];
      s += __shfl_xor(s, 1);
      s += __shfl_xor(s, 2);
      s += __shfl_xor(s, 4);
      s += __shfl_xor(s, 8);
      ps[r] = s;                    // own-half dot for rows q*4+r (all lanes)
    }

    // exchange halves (parity double-buffered)
    float* pb = &pairbuf[(it & 1) * 128];
    if (li == 0) *(f32x4*)&pb[(p * 2 + h) * 16 + q * 4] = ps;
    asm volatile("s_waitcnt lgkmcnt(0)\n\ts_barrier" ::: "memory");
    f32x4 po = *(const f32x4*)&pb[(p * 2 + (h ^ 1)) * 16 + q * 4];

    float g[4];
#pragma unroll
    for (int r = 0; r < 4; ++r)
      g[r] = 1.f / (1.f + __expf(-(ps[r] + po[r] + bp0)));

    const int rowb = R0 + it * 64 + q * 4;
    // gv store: BOTH halves store identical value to same addr (keeps the
    // per-wave VMEM store count uniform at 17; same-value race is benign)
    {
      f32x4 gv; gv.x = g[0]; gv.y = g[1]; gv.z = g[2]; gv.w = g[3];
      if (li == 0) *(f32x4*)&ws_pred[(size_t)kc * 8192 + rowb] = gv;
    }
    // 16 c_emb scalar stores
#pragma unroll
    for (int i = 0; i < 4; ++i) {
      int eg = h * 4 + i;
#pragma unroll
      for (int r = 0; r < 4; ++r) {
        float pos = acc[i][r], neg = acc[i + 4][r];
        out[(size_t)(rowb + r) * 8192 + kc * 128 + eg * 16 + li] =
            neg + (pos - neg) * g[r];
      }
    }

    // retire own A-prefetch: 4 loads are older than exactly the 17 stores
    // issued above -> vmcnt(17) drains the loads, leaves stores in flight.
    if (it < 7) asm volatile("s_waitcnt vmcnt(17)" ::: "memory");
    cur ^= 1;
  }
}

// ---------------- kernel 3: transpose ws_pred -> c_pred, c_int ----------------
__global__ __launch_bounds__(256)
void pred_tr_kernel(const float* __restrict__ ws_pred, float* __restrict__ out) {
  __shared__ float T[64][65];
  const int t = threadIdx.x;
  const int b0 = blockIdx.x * 64;

  {
    int kc = t >> 2;
    int j0 = (t & 3) * 16;
    const float* src = ws_pred + (size_t)kc * 8192 + b0 + j0;
#pragma unroll
    for (int i = 0; i < 4; ++i) {
      f32x4 v = *(const f32x4*)(src + i * 4);
      T[kc][j0 + i * 4 + 0] = v.x;
      T[kc][j0 + i * 4 + 1] = v.y;
      T[kc][j0 + i * 4 + 2] = v.z;
      T[kc][j0 + i * 4 + 3] = v.w;
    }
  }
  __syncthreads();
  {
    int bl = t & 63;
    int kq = (t >> 6) * 16;
#pragma unroll
    for (int i = 0; i < 4; ++i) {
      f32x4 v;
      v.x = T[kq + i * 4 + 0][bl];
      v.y = T[kq + i * 4 + 1][bl];
      v.z = T[kq + i * 4 + 2][bl];
      v.w = T[kq + i * 4 + 3][bl];
      *(f32x4*)&out[CPRED_OFF + (size_t)(b0 + bl) * 64 + kq + i * 4] = v;
      *(f32x4*)&out[CINT_OFF + (size_t)(b0 + bl) * 64 + kq + i * 4] = v;
    }
  }
}

extern "C" void kernel_launch(void* const* d_in, const int* in_sizes, int n_in,
                              void* d_out, int out_size, void* d_ws, size_t ws_size,
                              hipStream_t stream) {
  (void)in_sizes; (void)n_in; (void)out_size; (void)ws_size;
  const float* x  = (const float*)d_in[0];
  const float* We = (const float*)d_in[1];
  const float* be = (const float*)d_in[2];
  const float* Wc = (const float*)d_in[3];
  const float* bc = (const float*)d_in[4];
  const float* wp = (const float*)d_in[5];
  const float* bp = (const float*)d_in[6];
  float* out = (float*)d_out;

  // ws layout: We_bf16 (512KB) | Wc_bf16 (4MB) | emb_bf16 (2MB) | ws_pred (2MB f32)
  short* we_bf  = (short*)d_ws;
  short* wc_bf  = we_bf + 262144;
  short* emb_bf = wc_bf + 2097152;
  float* ws_pred = (float*)(emb_bf + 1048576);

  conv2_kernel<<<2304, 256, 0, stream>>>(We, we_bf, 65536, Wc, wc_bf, 524288);
  gemm1_kernel<<<512, 256, 0, stream>>>(x, we_bf, be, out + EMB_OFF, emb_bf);
  gemm2_kernel<<<1024, 512, 0, stream>>>(emb_bf, wc_bf, bc, wp, bp, ws_pred, out);
  pred_tr_kernel<<<128, 256, 0, stream>>>(ws_pred, out);
}